// Round 1
// baseline (1990.899 us; speedup 1.0000x reference)
//
#include <hip/hip_runtime.h>
#include <hip/hip_bf16.h>
#include <math.h>

#define BZ 64
#define NQ 100
#define NCLS 1203
#define NO_OBJ 1202
constexpr double HUNG_INF = 1e18;

// ---------------- kernel A0: per-row double softmax stats ----------------
__global__ __launch_bounds__(64) void rowstats_kernel(
    const float* __restrict__ lab_preds,
    double* __restrict__ rowmax, double* __restrict__ rowsum) {
  const int r = blockIdx.x;
  const int t = threadIdx.x;
  const float* row = lab_preds + (size_t)r * NCLS;
  double mx = -HUNG_INF;
  for (int c = t; c < NCLS; c += 64) mx = fmax(mx, (double)row[c]);
#pragma unroll
  for (int off = 32; off; off >>= 1) mx = fmax(mx, __shfl_xor(mx, off));
  double s = 0.0;
  for (int c = t; c < NCLS; c += 64) s += exp((double)row[c] - mx);
#pragma unroll
  for (int off = 32; off; off >>= 1) s += __shfl_xor(s, off);
  if (t == 0) { rowmax[r] = mx; rowsum[r] = s; }
}

// ---------------- kernel A: per-batch cost matrix + Hungarian (JV) ----------------
__global__ __launch_bounds__(64) void match_kernel(
    const int* __restrict__ labs, const float* __restrict__ lab_preds,
    const float* __restrict__ bbox, const float* __restrict__ bbox_preds,
    const double* __restrict__ rowmax, const double* __restrict__ rowsum,
    int* __restrict__ gt_idx) {
  __shared__ double Csh[NQ * NQ];                 // cost[pred][target]
  __shared__ double sh_u[NQ + 1], sh_v[NQ + 1], sh_minv[NQ + 1];
  __shared__ int sh_p[NQ + 1], sh_way[NQ + 1], sh_used[NQ + 1];
  __shared__ int labs_sh[NQ];
  __shared__ double pxy[NQ][4], txy[NQ][4], pcx[NQ][4], tcx[NQ][4];
  __shared__ double areaP[NQ], areaT[NQ], rmax[NQ], rsum[NQ];

  const int b = blockIdx.x, t = threadIdx.x;

  // stage per-batch data into LDS (doubles, mirroring the reference's f64 cast)
  for (int j = t; j < NQ; j += 64) {
    labs_sh[j] = labs[b * NQ + j];
    const float* tb = bbox + ((size_t)b * NQ + j) * 4;
    double cx = tb[0], cy = tb[1], w = tb[2], h = tb[3];
    tcx[j][0] = cx; tcx[j][1] = cy; tcx[j][2] = w; tcx[j][3] = h;
    double x1 = cx - w * 0.5, y1 = cy - h * 0.5, x2 = cx + w * 0.5, y2 = cy + h * 0.5;
    txy[j][0] = x1; txy[j][1] = y1; txy[j][2] = x2; txy[j][3] = y2;
    areaT[j] = (x2 - x1) * (y2 - y1);
    const float* pb = bbox_preds + ((size_t)b * NQ + j) * 4;
    cx = pb[0]; cy = pb[1]; w = pb[2]; h = pb[3];
    pcx[j][0] = cx; pcx[j][1] = cy; pcx[j][2] = w; pcx[j][3] = h;
    x1 = cx - w * 0.5; y1 = cy - h * 0.5; x2 = cx + w * 0.5; y2 = cy + h * 0.5;
    pxy[j][0] = x1; pxy[j][1] = y1; pxy[j][2] = x2; pxy[j][3] = y2;
    areaP[j] = (x2 - x1) * (y2 - y1);
    rmax[j] = rowmax[b * NQ + j];
    rsum[j] = rowsum[b * NQ + j];
  }
  __syncthreads();

  // fill cost matrix
  for (int idx = t; idx < NQ * NQ; idx += 64) {
    const int i = idx / NQ, j = idx - i * NQ;
    double pc = exp((double)lab_preds[((size_t)b * NQ + i) * NCLS + labs_sh[j]] - rmax[i]) / rsum[i];
    double cb = fabs(pcx[i][0] - tcx[j][0]) + fabs(pcx[i][1] - tcx[j][1])
              + fabs(pcx[i][2] - tcx[j][2]) + fabs(pcx[i][3] - tcx[j][3]);
    double ltx = fmax(pxy[i][0], txy[j][0]);
    double lty = fmax(pxy[i][1], txy[j][1]);
    double rbx = fmin(pxy[i][2], txy[j][2]);
    double rby = fmin(pxy[i][3], txy[j][3]);
    double inter = fmax(rbx - ltx, 0.0) * fmax(rby - lty, 0.0);
    double uni = areaP[i] + areaT[j] - inter;
    double iou = inter / fmax(uni, 1e-9);
    Csh[idx] = -pc + cb + (1.0 - iou);
  }

  // init potentials / matching state
  for (int j = t; j <= NQ; j += 64) { sh_u[j] = 0.0; sh_v[j] = 0.0; sh_p[j] = 0; sh_way[j] = 0; }
  __syncthreads();

  // Jonker-Volgenant with per-column parallelism (exactly mirrors the numpy _lsa)
  for (int i = 1; i <= NQ; ++i) {
    if (t == 0) sh_p[0] = i;
    for (int j = t; j <= NQ; j += 64) { sh_minv[j] = HUNG_INF; sh_used[j] = 0; }
    __syncthreads();
    int j0 = 0;
    while (true) {
      if (t == 0) sh_used[j0] = 1;
      __syncthreads();
      const int i0 = sh_p[j0];
      const double ui0 = sh_u[i0];
      double bestv = HUNG_INF; int bestj = NQ + 1;
      for (int j = t + 1; j <= NQ; j += 64) {
        if (!sh_used[j]) {
          double cur = Csh[(i0 - 1) * NQ + (j - 1)] - ui0 - sh_v[j];
          double mv = sh_minv[j];
          if (cur < mv) { mv = cur; sh_minv[j] = cur; sh_way[j] = j0; }
          if (mv < bestv || (mv == bestv && j < bestj)) { bestv = mv; bestj = j; }
        }
      }
      // wave-wide lexicographic argmin (numpy argmin = first minimal index)
#pragma unroll
      for (int off = 32; off; off >>= 1) {
        double ov = __shfl_xor(bestv, off);
        int oj = __shfl_xor(bestj, off);
        if (ov < bestv || (ov == bestv && oj < bestj)) { bestv = ov; bestj = oj; }
      }
      const int j1 = bestj;
      const double delta = bestv;
      __syncthreads();
      for (int j = t; j <= NQ; j += 64) {
        if (sh_used[j]) { sh_u[sh_p[j]] += delta; sh_v[j] -= delta; }
        else sh_minv[j] -= delta;
      }
      __syncthreads();
      j0 = j1;
      if (sh_p[j0] == 0) break;
    }
    if (t == 0) {  // augment along stored path
      int jj = j0;
      while (jj != 0) { int jn = sh_way[jj]; sh_p[jj] = sh_p[jn]; jj = jn; }
    }
    __syncthreads();
  }

  // col_of_row: gt_idx[row p[j]-1] = j-1
  for (int j = t + 1; j <= NQ; j += 64) gt_idx[b * NQ + sh_p[j] - 1] = j - 1;
}

// ---------------- kernel B: float32 loss partials ----------------
__global__ __launch_bounds__(256) void loss_kernel(
    const int* __restrict__ labs, const float* __restrict__ lab_preds,
    const float* __restrict__ bbox, const float* __restrict__ bbox_preds,
    const int* __restrict__ gt_idx,
    double* __restrict__ acc, int* __restrict__ cnt_out) {
  const int b = blockIdx.x;
  const int wave = threadIdx.x >> 6, lane = threadIdx.x & 63;
  double lab_acc = 0.0, l1_acc = 0.0, iou_acc = 0.0;
  int cnt_acc = 0;
  for (int i = wave; i < NQ; i += 4) {
    const float* row = lab_preds + ((size_t)b * NQ + i) * NCLS;
    float mx = -3.402823466e38f; int amx = NCLS;
    for (int c = lane; c < NCLS; c += 64) {
      float vv = row[c];
      if (vv > mx) { mx = vv; amx = c; }
    }
#pragma unroll
    for (int off = 32; off; off >>= 1) {
      float ov = __shfl_xor(mx, off); int oi = __shfl_xor(amx, off);
      if (ov > mx || (ov == mx && oi < amx)) { mx = ov; amx = oi; }
    }
    float s = 0.0f;
    for (int c = lane; c < NCLS; c += 64) s += expf(row[c] - mx);
#pragma unroll
    for (int off = 32; off; off >>= 1) s += __shfl_xor(s, off);
    if (lane == 0) {
      const int g = gt_idx[b * NQ + i];
      const int nl = labs[b * NQ + g];
      float pg = expf(row[nl] - mx) / s;
      lab_acc -= (double)pg;                      // -p[gt_label]
      if (nl != NO_OBJ && nl == amx) {
        cnt_acc++;
        const float* pb = bbox_preds + ((size_t)b * NQ + i) * 4;
        const float* tb = bbox + ((size_t)b * NQ + g) * 4;
        float l1 = fabsf(tb[0] - pb[0]) + fabsf(tb[1] - pb[1])
                 + fabsf(tb[2] - pb[2]) + fabsf(tb[3] - pb[3]);
        l1_acc += (double)l1;
        float px1 = pb[0] - pb[2] * 0.5f, py1 = pb[1] - pb[3] * 0.5f;
        float px2 = pb[0] + pb[2] * 0.5f, py2 = pb[1] + pb[3] * 0.5f;
        float tx1 = tb[0] - tb[2] * 0.5f, ty1 = tb[1] - tb[3] * 0.5f;
        float tx2 = tb[0] + tb[2] * 0.5f, ty2 = tb[1] + tb[3] * 0.5f;
        float ltx = fmaxf(px1, tx1), lty = fmaxf(py1, ty1);
        float rbx = fminf(px2, tx2), rby = fminf(py2, ty2);
        float inter = fmaxf(rbx - ltx, 0.0f) * fmaxf(rby - lty, 0.0f);
        float uni = (px2 - px1) * (py2 - py1) + (tx2 - tx1) * (ty2 - ty1) - inter;
        float iou = inter / fmaxf(uni, 1e-9f);
        iou_acc += (double)(1.0f - iou);
      }
    }
  }
  __shared__ double s_lab[4], s_l1[4], s_iou[4];
  __shared__ int s_cnt[4];
  if (lane == 0) { s_lab[wave] = lab_acc; s_l1[wave] = l1_acc; s_iou[wave] = iou_acc; s_cnt[wave] = cnt_acc; }
  __syncthreads();
  if (threadIdx.x == 0) {
    double a = 0.0, bsum = 0.0, c = 0.0; int n = 0;
    for (int wv = 0; wv < 4; ++wv) { a += s_lab[wv]; bsum += s_l1[wv]; c += s_iou[wv]; n += s_cnt[wv]; }
    atomicAdd(&acc[0], a);
    atomicAdd(&acc[1], bsum);
    atomicAdd(&acc[2], c);
    atomicAdd(cnt_out, n);
  }
}

// ---------------- kernel C: combine ----------------
__global__ void finalize_kernel(const double* __restrict__ acc, const int* __restrict__ cnt,
                                float* __restrict__ out) {
  int n = *cnt; if (n < 1) n = 1;
  out[0] = (float)(acc[0] / (double)(BZ * NQ) + acc[1] + acc[2] / (double)n);
}

extern "C" void kernel_launch(void* const* d_in, const int* in_sizes, int n_in,
                              void* d_out, int out_size, void* d_ws, size_t ws_size,
                              hipStream_t stream) {
  const int*   labs       = (const int*)d_in[0];
  const float* lab_preds  = (const float*)d_in[1];
  const float* bbox       = (const float*)d_in[2];
  const float* bbox_preds = (const float*)d_in[3];

  char* ws = (char*)d_ws;
  int*    gt_idx = (int*)ws;                         // 64*100*4 = 25600 B
  double* acc    = (double*)(ws + 25600);            // 3 doubles
  int*    cnt    = (int*)(ws + 25624);               // 1 int
  double* rowmax = (double*)(ws + 25632);            // 6400 doubles
  double* rowsum = (double*)(ws + 25632 + 51200);    // 6400 doubles

  hipMemsetAsync(ws + 25600, 0, 32, stream);         // zero accumulators
  rowstats_kernel<<<BZ * NQ, 64, 0, stream>>>(lab_preds, rowmax, rowsum);
  match_kernel<<<BZ, 64, 0, stream>>>(labs, lab_preds, bbox, bbox_preds, rowmax, rowsum, gt_idx);
  loss_kernel<<<BZ, 256, 0, stream>>>(labs, lab_preds, bbox, bbox_preds, gt_idx, acc, cnt);
  finalize_kernel<<<1, 1, 0, stream>>>(acc, cnt, (float*)d_out);
}

// Round 2
// 1017.982 us; speedup vs baseline: 1.9557x; 1.9557x over previous
//
#include <hip/hip_runtime.h>
#include <hip/hip_bf16.h>
#include <math.h>

#define BZ 64
#define NQ 100
#define NCLS 1203
#define NO_OBJ 1202
constexpr double HUNG_INF = 1e18;

// ---------------- kernel A0: per-row double softmax stats ----------------
__global__ __launch_bounds__(64) void rowstats_kernel(
    const float* __restrict__ lab_preds,
    double* __restrict__ rowmax, double* __restrict__ rowsum) {
  const int r = blockIdx.x;
  const int t = threadIdx.x;
  const float* row = lab_preds + (size_t)r * NCLS;
  double mx = -HUNG_INF;
  for (int c = t; c < NCLS; c += 64) mx = fmax(mx, (double)row[c]);
#pragma unroll
  for (int off = 32; off; off >>= 1) mx = fmax(mx, __shfl_xor(mx, off));
  double s = 0.0;
  for (int c = t; c < NCLS; c += 64) s += exp((double)row[c] - mx);
#pragma unroll
  for (int off = 32; off; off >>= 1) s += __shfl_xor(s, off);
  if (t == 0) { rowmax[r] = mx; rowsum[r] = s; }
}

// ---------------- kernel A: per-batch cost matrix + Hungarian (JV) ----------------
// Register-resident JV: lane l owns columns (l+1) and (l+65). All per-column
// state (minv, v, way, used, p) lives in registers; only the cost matrix and
// the row potentials u[] stay in LDS. No __syncthreads inside the phase loop
// (single wave; DS ops are in-order within a wave; all RMW addresses are
// provably disjoint per iteration). FP op order matches the numpy reference
// element-for-element, and argmin tie-breaking is first-min-index.
__global__ __launch_bounds__(64) void match_kernel(
    const int* __restrict__ labs, const float* __restrict__ lab_preds,
    const float* __restrict__ bbox, const float* __restrict__ bbox_preds,
    const double* __restrict__ rowmax, const double* __restrict__ rowsum,
    int* __restrict__ gt_idx) {
  __shared__ double Csh[NQ * NQ];   // cost[pred][target], 80 KB
  __shared__ double u_sh[NQ + 1];
  __shared__ int labs_sh[NQ];
  __shared__ double pxy[NQ][4], txy[NQ][4], pcx[NQ][4], tcx[NQ][4];
  __shared__ double areaP[NQ], areaT[NQ], rmax[NQ], rsum[NQ];

  const int b = blockIdx.x, t = threadIdx.x;
  const int lane = t;

  // stage per-batch data into LDS (doubles, mirroring the reference's f64 cast)
  for (int j = t; j < NQ; j += 64) {
    labs_sh[j] = labs[b * NQ + j];
    const float* tb = bbox + ((size_t)b * NQ + j) * 4;
    double cx = tb[0], cy = tb[1], w = tb[2], h = tb[3];
    tcx[j][0] = cx; tcx[j][1] = cy; tcx[j][2] = w; tcx[j][3] = h;
    double x1 = cx - w * 0.5, y1 = cy - h * 0.5, x2 = cx + w * 0.5, y2 = cy + h * 0.5;
    txy[j][0] = x1; txy[j][1] = y1; txy[j][2] = x2; txy[j][3] = y2;
    areaT[j] = (x2 - x1) * (y2 - y1);
    const float* pb = bbox_preds + ((size_t)b * NQ + j) * 4;
    cx = pb[0]; cy = pb[1]; w = pb[2]; h = pb[3];
    pcx[j][0] = cx; pcx[j][1] = cy; pcx[j][2] = w; pcx[j][3] = h;
    x1 = cx - w * 0.5; y1 = cy - h * 0.5; x2 = cx + w * 0.5; y2 = cy + h * 0.5;
    pxy[j][0] = x1; pxy[j][1] = y1; pxy[j][2] = x2; pxy[j][3] = y2;
    areaP[j] = (x2 - x1) * (y2 - y1);
    rmax[j] = rowmax[b * NQ + j];
    rsum[j] = rowsum[b * NQ + j];
  }
  for (int j = t; j <= NQ; j += 64) u_sh[j] = 0.0;
  __syncthreads();

  // fill cost matrix
  for (int idx = t; idx < NQ * NQ; idx += 64) {
    const int i = idx / NQ, j = idx - i * NQ;
    double pc = exp((double)lab_preds[((size_t)b * NQ + i) * NCLS + labs_sh[j]] - rmax[i]) / rsum[i];
    double cb = fabs(pcx[i][0] - tcx[j][0]) + fabs(pcx[i][1] - tcx[j][1])
              + fabs(pcx[i][2] - tcx[j][2]) + fabs(pcx[i][3] - tcx[j][3]);
    double ltx = fmax(pxy[i][0], txy[j][0]);
    double lty = fmax(pxy[i][1], txy[j][1]);
    double rbx = fmin(pxy[i][2], txy[j][2]);
    double rby = fmin(pxy[i][3], txy[j][3]);
    double inter = fmax(rbx - ltx, 0.0) * fmax(rby - lty, 0.0);
    double uni = areaP[i] + areaT[j] - inter;
    double iou = inter / fmax(uni, 1e-9);
    Csh[idx] = -pc + cb + (1.0 - iou);
  }
  __syncthreads();

  // -------- register-resident Jonker-Volgenant --------
  const bool has1 = (lane + 65 <= NQ);   // lanes 0..35 own a second column
  double v0 = 0.0, v1 = 0.0;
  int p0c = 0, p1c = 0;                  // p[] for my columns (0 = unmatched)

  for (int i = 1; i <= NQ; ++i) {
    double minv0 = HUNG_INF, minv1 = HUNG_INF;
    int way0 = 0, way1 = 0;
    bool used0 = false, used1 = false;
    int j0 = 0;
    int i0 = i;                          // p[0] = i
    while (true) {
      // mark j0 used (j0==0 handled implicitly: lane 0 applies u[i] += delta)
      if (j0 == lane + 1) used0 = true;
      if (j0 == lane + 65) used1 = true;

      const double ui0 = u_sh[i0];                         // broadcast read
      const double* crow = &Csh[(i0 - 1) * NQ];
      const double c0 = crow[lane];                        // col lane+1
      const double c1 = has1 ? crow[lane + 64] : 0.0;      // col lane+65

      if (!used0) {
        double cur = (c0 - ui0) - v0;
        if (cur < minv0) { minv0 = cur; way0 = j0; }
      }
      if (has1 && !used1) {
        double cur = (c1 - ui0) - v1;
        if (cur < minv1) { minv1 = cur; way1 = j0; }
      }
      double a0 = used0 ? HUNG_INF : minv0;
      double a1 = (has1 && !used1) ? minv1 : HUNG_INF;
      double m = fmin(a0, a1);
#pragma unroll
      for (int off = 32; off; off >>= 1) m = fmin(m, __shfl_xor(m, off));
      // first-min-index: cols 1..64 (reg0, lane order) precede 65..100 (reg1)
      unsigned long long b0 = __ballot(a0 == m);
      int j1;
      if (b0) j1 = (int)__ffsll(b0);               // = lane+1
      else {
        unsigned long long b1 = __ballot(a1 == m);
        j1 = (int)__ffsll(b1) + 64;                // = lane+65
      }
      const double delta = m;

      // potential updates (same per-element op order as reference)
      if (used0)        { v0 -= delta; u_sh[p0c] += delta; }
      else              { minv0 -= delta; }
      if (has1) {
        if (used1)      { v1 -= delta; u_sh[p1c] += delta; }
        else            { minv1 -= delta; }
      }
      if (lane == 0) u_sh[i] += delta;             // j0=0 is always used

      // j0 = j1; if p[j0]==0 break
      int lj = (j1 <= 64) ? (j1 - 1) : (j1 - 65);
      int pa = __shfl(p0c, lj), pb = __shfl(p1c, lj);
      int pj1 = (j1 <= 64) ? pa : pb;
      j0 = j1; i0 = pj1;
      if (pj1 == 0) break;
    }
    // augment along way[] chain (uniform scalar walk via shuffles)
    int jj = j0;
    while (jj != 0) {
      int lj = (jj <= 64) ? (jj - 1) : (jj - 65);
      int wa = __shfl(way0, lj), wb = __shfl(way1, lj);
      int jn = (jj <= 64) ? wa : wb;
      int pn;
      if (jn == 0) pn = i;
      else {
        int ln = (jn <= 64) ? (jn - 1) : (jn - 65);
        int qa = __shfl(p0c, ln), qb = __shfl(p1c, ln);
        pn = (jn <= 64) ? qa : qb;
      }
      if (jj == lane + 1)  p0c = pn;
      if (jj == lane + 65) p1c = pn;
      jj = jn;
    }
  }

  // col_of_row: gt_idx[p[j]-1] = j-1
  gt_idx[b * NQ + p0c - 1] = lane;                 // col lane+1
  if (has1) gt_idx[b * NQ + p1c - 1] = lane + 64;  // col lane+65
}

// ---------------- kernel B: float32 loss partials ----------------
__global__ __launch_bounds__(256) void loss_kernel(
    const int* __restrict__ labs, const float* __restrict__ lab_preds,
    const float* __restrict__ bbox, const float* __restrict__ bbox_preds,
    const int* __restrict__ gt_idx,
    double* __restrict__ acc, int* __restrict__ cnt_out) {
  const int b = blockIdx.x;
  const int wave = threadIdx.x >> 6, lane = threadIdx.x & 63;
  double lab_acc = 0.0, l1_acc = 0.0, iou_acc = 0.0;
  int cnt_acc = 0;
  for (int i = wave; i < NQ; i += 4) {
    const float* row = lab_preds + ((size_t)b * NQ + i) * NCLS;
    float mx = -3.402823466e38f; int amx = NCLS;
    for (int c = lane; c < NCLS; c += 64) {
      float vv = row[c];
      if (vv > mx) { mx = vv; amx = c; }
    }
#pragma unroll
    for (int off = 32; off; off >>= 1) {
      float ov = __shfl_xor(mx, off); int oi = __shfl_xor(amx, off);
      if (ov > mx || (ov == mx && oi < amx)) { mx = ov; amx = oi; }
    }
    float s = 0.0f;
    for (int c = lane; c < NCLS; c += 64) s += expf(row[c] - mx);
#pragma unroll
    for (int off = 32; off; off >>= 1) s += __shfl_xor(s, off);
    if (lane == 0) {
      const int g = gt_idx[b * NQ + i];
      const int nl = labs[b * NQ + g];
      float pg = expf(row[nl] - mx) / s;
      lab_acc -= (double)pg;                      // -p[gt_label]
      if (nl != NO_OBJ && nl == amx) {
        cnt_acc++;
        const float* pb = bbox_preds + ((size_t)b * NQ + i) * 4;
        const float* tb = bbox + ((size_t)b * NQ + g) * 4;
        float l1 = fabsf(tb[0] - pb[0]) + fabsf(tb[1] - pb[1])
                 + fabsf(tb[2] - pb[2]) + fabsf(tb[3] - pb[3]);
        l1_acc += (double)l1;
        float px1 = pb[0] - pb[2] * 0.5f, py1 = pb[1] - pb[3] * 0.5f;
        float px2 = pb[0] + pb[2] * 0.5f, py2 = pb[1] + pb[3] * 0.5f;
        float tx1 = tb[0] - tb[2] * 0.5f, ty1 = tb[1] - tb[3] * 0.5f;
        float tx2 = tb[0] + tb[2] * 0.5f, ty2 = tb[1] + tb[3] * 0.5f;
        float ltx = fmaxf(px1, tx1), lty = fmaxf(py1, ty1);
        float rbx = fminf(px2, tx2), rby = fminf(py2, ty2);
        float inter = fmaxf(rbx - ltx, 0.0f) * fmaxf(rby - lty, 0.0f);
        float uni = (px2 - px1) * (py2 - py1) + (tx2 - tx1) * (ty2 - ty1) - inter;
        float iou = inter / fmaxf(uni, 1e-9f);
        iou_acc += (double)(1.0f - iou);
      }
    }
  }
  __shared__ double s_lab[4], s_l1[4], s_iou[4];
  __shared__ int s_cnt[4];
  if (lane == 0) { s_lab[wave] = lab_acc; s_l1[wave] = l1_acc; s_iou[wave] = iou_acc; s_cnt[wave] = cnt_acc; }
  __syncthreads();
  if (threadIdx.x == 0) {
    double a = 0.0, bsum = 0.0, c = 0.0; int n = 0;
    for (int wv = 0; wv < 4; ++wv) { a += s_lab[wv]; bsum += s_l1[wv]; c += s_iou[wv]; n += s_cnt[wv]; }
    atomicAdd(&acc[0], a);
    atomicAdd(&acc[1], bsum);
    atomicAdd(&acc[2], c);
    atomicAdd(cnt_out, n);
  }
}

// ---------------- kernel C: combine ----------------
__global__ void finalize_kernel(const double* __restrict__ acc, const int* __restrict__ cnt,
                                float* __restrict__ out) {
  int n = *cnt; if (n < 1) n = 1;
  out[0] = (float)(acc[0] / (double)(BZ * NQ) + acc[1] + acc[2] / (double)n);
}

extern "C" void kernel_launch(void* const* d_in, const int* in_sizes, int n_in,
                              void* d_out, int out_size, void* d_ws, size_t ws_size,
                              hipStream_t stream) {
  const int*   labs       = (const int*)d_in[0];
  const float* lab_preds  = (const float*)d_in[1];
  const float* bbox       = (const float*)d_in[2];
  const float* bbox_preds = (const float*)d_in[3];

  char* ws = (char*)d_ws;
  int*    gt_idx = (int*)ws;                         // 64*100*4 = 25600 B
  double* acc    = (double*)(ws + 25600);            // 3 doubles
  int*    cnt    = (int*)(ws + 25624);               // 1 int
  double* rowmax = (double*)(ws + 25632);            // 6400 doubles
  double* rowsum = (double*)(ws + 25632 + 51200);    // 6400 doubles

  hipMemsetAsync(ws + 25600, 0, 32, stream);         // zero accumulators
  rowstats_kernel<<<BZ * NQ, 64, 0, stream>>>(lab_preds, rowmax, rowsum);
  match_kernel<<<BZ, 64, 0, stream>>>(labs, lab_preds, bbox, bbox_preds, rowmax, rowsum, gt_idx);
  loss_kernel<<<BZ, 256, 0, stream>>>(labs, lab_preds, bbox, bbox_preds, gt_idx, acc, cnt);
  finalize_kernel<<<1, 1, 0, stream>>>(acc, cnt, (float*)d_out);
}

// Round 3
// 753.897 us; speedup vs baseline: 2.6408x; 1.3503x over previous
//
#include <hip/hip_runtime.h>
#include <hip/hip_bf16.h>
#include <math.h>

#define BZ 64
#define NQ 100
#define NCLS 1203
#define NO_OBJ 1202
constexpr double HUNG_INF = 1e18;

// ---- cross-lane helpers (VALU/scalar, no DS ops) ----
__device__ inline double readlane_f64(double x, int l) {
  int lo = __builtin_amdgcn_readlane(__double2loint(x), l);
  int hi = __builtin_amdgcn_readlane(__double2hiint(x), l);
  return __hiloint2double(hi, lo);
}

template <int CTRL>
__device__ inline double dpp_min_f64(double x) {
  // old = src so lanes with invalid DPP source keep x (min(x,x)=x harmless)
  int lo = __double2loint(x), hi = __double2hiint(x);
  int nlo = __builtin_amdgcn_update_dpp(lo, lo, CTRL, 0xF, 0xF, false);
  int nhi = __builtin_amdgcn_update_dpp(hi, hi, CTRL, 0xF, 0xF, false);
  return fmin(x, __hiloint2double(nhi, nlo));
}

// min over all 64 lanes -> returned as wave-uniform scalar (exact value preserved)
__device__ inline double wave_min_f64(double x) {
  x = dpp_min_f64<0xB1>(x);    // quad_perm [1,0,3,2]  : xor 1
  x = dpp_min_f64<0x4E>(x);    // quad_perm [2,3,0,1]  : xor 2
  x = dpp_min_f64<0x141>(x);   // row_half_mirror      : xor 7
  x = dpp_min_f64<0x128>(x);   // row_ror:8            : xor 8  (span{1,2,7,8}=16)
  x = dpp_min_f64<0x142>(x);   // row_bcast15: lanes16-31 get row0 min, 48-63 get row2 min
  x = dpp_min_f64<0x143>(x);   // row_bcast31: lanes 48-63 now hold global min
  return readlane_f64(x, 63);
}

// ---------------- kernel A0: per-row double softmax stats ----------------
__global__ __launch_bounds__(64) void rowstats_kernel(
    const float* __restrict__ lab_preds,
    double* __restrict__ rowmax, double* __restrict__ rowsum) {
  const int r = blockIdx.x;
  const int t = threadIdx.x;
  const float* row = lab_preds + (size_t)r * NCLS;
  double mx = -HUNG_INF;
  for (int c = t; c < NCLS; c += 64) mx = fmax(mx, (double)row[c]);
#pragma unroll
  for (int off = 32; off; off >>= 1) mx = fmax(mx, __shfl_xor(mx, off));
  double s = 0.0;
  for (int c = t; c < NCLS; c += 64) s += exp((double)row[c] - mx);
#pragma unroll
  for (int off = 32; off; off >>= 1) s += __shfl_xor(s, off);
  if (t == 0) { rowmax[r] = mx; rowsum[r] = s; }
}

// ---------------- kernel A: per-batch cost matrix + Hungarian (JV) ----------------
// Register-resident JV: lane l owns columns (l+1) and (l+65). Per-column state
// (minv, v, way, used, p) in registers. Critical chain per Dijkstra step:
// readlane(p) -> ds_read cost row -> VALU -> DPP min-reduce -> ballot.
// FP op order matches the numpy reference element-for-element; argmin
// tie-break is first-min-index via ballot+ffs.
__global__ __launch_bounds__(64) void match_kernel(
    const int* __restrict__ labs, const float* __restrict__ lab_preds,
    const float* __restrict__ bbox, const float* __restrict__ bbox_preds,
    const double* __restrict__ rowmax, const double* __restrict__ rowsum,
    int* __restrict__ gt_idx) {
  __shared__ double Csh[NQ * NQ];   // cost[pred][target], 80 KB
  __shared__ double u_sh[NQ + 1];
  __shared__ int labs_sh[NQ];
  __shared__ double pxy[NQ][4], txy[NQ][4], pcx[NQ][4], tcx[NQ][4];
  __shared__ double areaP[NQ], areaT[NQ], rmax[NQ], rsum[NQ];

  const int b = blockIdx.x, t = threadIdx.x;
  const int lane = t;

  // stage per-batch data into LDS (doubles, mirroring the reference's f64 cast)
  for (int j = t; j < NQ; j += 64) {
    labs_sh[j] = labs[b * NQ + j];
    const float* tb = bbox + ((size_t)b * NQ + j) * 4;
    double cx = tb[0], cy = tb[1], w = tb[2], h = tb[3];
    tcx[j][0] = cx; tcx[j][1] = cy; tcx[j][2] = w; tcx[j][3] = h;
    double x1 = cx - w * 0.5, y1 = cy - h * 0.5, x2 = cx + w * 0.5, y2 = cy + h * 0.5;
    txy[j][0] = x1; txy[j][1] = y1; txy[j][2] = x2; txy[j][3] = y2;
    areaT[j] = (x2 - x1) * (y2 - y1);
    const float* pb = bbox_preds + ((size_t)b * NQ + j) * 4;
    cx = pb[0]; cy = pb[1]; w = pb[2]; h = pb[3];
    pcx[j][0] = cx; pcx[j][1] = cy; pcx[j][2] = w; pcx[j][3] = h;
    x1 = cx - w * 0.5; y1 = cy - h * 0.5; x2 = cx + w * 0.5; y2 = cy + h * 0.5;
    pxy[j][0] = x1; pxy[j][1] = y1; pxy[j][2] = x2; pxy[j][3] = y2;
    areaP[j] = (x2 - x1) * (y2 - y1);
    rmax[j] = rowmax[b * NQ + j];
    rsum[j] = rowsum[b * NQ + j];
  }
  for (int j = t; j <= NQ; j += 64) u_sh[j] = 0.0;
  __syncthreads();

  // fill cost matrix
  for (int idx = t; idx < NQ * NQ; idx += 64) {
    const int i = idx / NQ, j = idx - i * NQ;
    double pc = exp((double)lab_preds[((size_t)b * NQ + i) * NCLS + labs_sh[j]] - rmax[i]) / rsum[i];
    double cb = fabs(pcx[i][0] - tcx[j][0]) + fabs(pcx[i][1] - tcx[j][1])
              + fabs(pcx[i][2] - tcx[j][2]) + fabs(pcx[i][3] - tcx[j][3]);
    double ltx = fmax(pxy[i][0], txy[j][0]);
    double lty = fmax(pxy[i][1], txy[j][1]);
    double rbx = fmin(pxy[i][2], txy[j][2]);
    double rby = fmin(pxy[i][3], txy[j][3]);
    double inter = fmax(rbx - ltx, 0.0) * fmax(rby - lty, 0.0);
    double uni = areaP[i] + areaT[j] - inter;
    double iou = inter / fmax(uni, 1e-9);
    Csh[idx] = -pc + cb + (1.0 - iou);
  }
  __syncthreads();

  // -------- register-resident Jonker-Volgenant --------
  const bool has1 = (lane + 65 <= NQ);   // lanes 0..35 own a second column
  double v0 = 0.0, v1 = 0.0;
  int p0c = 0, p1c = 0;                  // p[] for my columns (0 = unmatched)

  for (int i = 1; i <= NQ; ++i) {
    double minv0 = HUNG_INF, minv1 = HUNG_INF;
    int way0 = 0, way1 = 0;
    bool used0 = false, used1 = false;
    int j0 = 0;
    int i0 = i;                          // p[0] = i
    while (true) {
      // mark j0 used (j0==0 handled implicitly: lane 0 applies u[i] += delta)
      if (j0 == lane + 1) used0 = true;
      if (j0 == lane + 65) used1 = true;

      const double ui0 = u_sh[i0];                         // uniform LDS read
      const double* crow = &Csh[(i0 - 1) * NQ];
      const double c0 = crow[lane];                        // col lane+1
      const double c1 = has1 ? crow[lane + 64] : 0.0;      // col lane+65

      if (!used0) {
        double cur = (c0 - ui0) - v0;
        if (cur < minv0) { minv0 = cur; way0 = j0; }
      }
      if (has1 && !used1) {
        double cur = (c1 - ui0) - v1;
        if (cur < minv1) { minv1 = cur; way1 = j0; }
      }
      double a0 = used0 ? HUNG_INF : minv0;
      double a1 = (has1 && !used1) ? minv1 : HUNG_INF;

      const double delta = wave_min_f64(fmin(a0, a1));     // exact global min

      // first-min-index: cols 1..64 (reg0, lane order) precede 65..100 (reg1)
      unsigned long long bl0 = __ballot(a0 == delta);
      int j1, lj;
      if (bl0) { lj = (int)__ffsll(bl0) - 1; j1 = lj + 1; }
      else {
        unsigned long long bl1 = __ballot(a1 == delta);
        lj = (int)__ffsll(bl1) - 1; j1 = lj + 65;
      }

      // potential updates (same per-element op order as reference)
      if (used0)        { v0 -= delta; u_sh[p0c] += delta; }
      else              { minv0 -= delta; }
      if (has1) {
        if (used1)      { v1 -= delta; u_sh[p1c] += delta; }
        else            { minv1 -= delta; }
      }
      if (lane == 0) u_sh[i] += delta;             // j0=0 is always used

      // j0 = j1; if p[j0]==0 break   (lane lj is uniform -> v_readlane)
      int pj1 = (j1 <= 64) ? __builtin_amdgcn_readlane(p0c, lj)
                           : __builtin_amdgcn_readlane(p1c, lj);
      j0 = j1; i0 = pj1;
      if (pj1 == 0) break;
    }
    // augment along way[] chain (uniform scalar walk via readlane)
    int jj = j0;
    while (jj != 0) {
      int ljj = (jj <= 64) ? (jj - 1) : (jj - 65);
      int jn = (jj <= 64) ? __builtin_amdgcn_readlane(way0, ljj)
                          : __builtin_amdgcn_readlane(way1, ljj);
      int pn;
      if (jn == 0) pn = i;
      else {
        int ln = (jn <= 64) ? (jn - 1) : (jn - 65);
        pn = (jn <= 64) ? __builtin_amdgcn_readlane(p0c, ln)
                        : __builtin_amdgcn_readlane(p1c, ln);
      }
      if (jj == lane + 1)  p0c = pn;
      if (jj == lane + 65) p1c = pn;
      jj = jn;
    }
  }

  // col_of_row: gt_idx[p[j]-1] = j-1
  gt_idx[b * NQ + p0c - 1] = lane;                 // col lane+1
  if (has1) gt_idx[b * NQ + p1c - 1] = lane + 64;  // col lane+65
}

// ---------------- kernel B: float32 loss partials (one row per block) ----------------
__global__ __launch_bounds__(64) void loss_kernel(
    const int* __restrict__ labs, const float* __restrict__ lab_preds,
    const float* __restrict__ bbox, const float* __restrict__ bbox_preds,
    const int* __restrict__ gt_idx,
    double* __restrict__ acc, int* __restrict__ cnt_out) {
  const int r = blockIdx.x;            // r = b*NQ + i
  const int b = r / NQ, i = r - b * NQ;
  const int lane = threadIdx.x;
  const float* row = lab_preds + (size_t)r * NCLS;
  float mx = -3.402823466e38f; int amx = NCLS;
  for (int c = lane; c < NCLS; c += 64) {
    float vv = row[c];
    if (vv > mx) { mx = vv; amx = c; }
  }
#pragma unroll
  for (int off = 32; off; off >>= 1) {
    float ov = __shfl_xor(mx, off); int oi = __shfl_xor(amx, off);
    if (ov > mx || (ov == mx && oi < amx)) { mx = ov; amx = oi; }
  }
  float s = 0.0f;
  for (int c = lane; c < NCLS; c += 64) s += expf(row[c] - mx);
#pragma unroll
  for (int off = 32; off; off >>= 1) s += __shfl_xor(s, off);
  if (lane == 0) {
    const int g = gt_idx[r];
    const int nl = labs[b * NQ + g];
    float pg = expf(row[nl] - mx) / s;
    atomicAdd(&acc[0], -(double)pg);                 // -p[gt_label]
    if (nl != NO_OBJ && nl == amx) {
      const float* pb = bbox_preds + (size_t)r * 4;
      const float* tb = bbox + ((size_t)b * NQ + g) * 4;
      float l1 = fabsf(tb[0] - pb[0]) + fabsf(tb[1] - pb[1])
               + fabsf(tb[2] - pb[2]) + fabsf(tb[3] - pb[3]);
      float px1 = pb[0] - pb[2] * 0.5f, py1 = pb[1] - pb[3] * 0.5f;
      float px2 = pb[0] + pb[2] * 0.5f, py2 = pb[1] + pb[3] * 0.5f;
      float tx1 = tb[0] - tb[2] * 0.5f, ty1 = tb[1] - tb[3] * 0.5f;
      float tx2 = tb[0] + tb[2] * 0.5f, ty2 = tb[1] + tb[3] * 0.5f;
      float ltx = fmaxf(px1, tx1), lty = fmaxf(py1, ty1);
      float rbx = fminf(px2, tx2), rby = fminf(py2, ty2);
      float inter = fmaxf(rbx - ltx, 0.0f) * fmaxf(rby - lty, 0.0f);
      float uni = (px2 - px1) * (py2 - py1) + (tx2 - tx1) * (ty2 - ty1) - inter;
      float iou = inter / fmaxf(uni, 1e-9f);
      atomicAdd(&acc[1], (double)l1);
      atomicAdd(&acc[2], (double)(1.0f - iou));
      atomicAdd(cnt_out, 1);
    }
  }
}

// ---------------- kernel C: combine ----------------
__global__ void finalize_kernel(const double* __restrict__ acc, const int* __restrict__ cnt,
                                float* __restrict__ out) {
  int n = *cnt; if (n < 1) n = 1;
  out[0] = (float)(acc[0] / (double)(BZ * NQ) + acc[1] + acc[2] / (double)n);
}

extern "C" void kernel_launch(void* const* d_in, const int* in_sizes, int n_in,
                              void* d_out, int out_size, void* d_ws, size_t ws_size,
                              hipStream_t stream) {
  const int*   labs       = (const int*)d_in[0];
  const float* lab_preds  = (const float*)d_in[1];
  const float* bbox       = (const float*)d_in[2];
  const float* bbox_preds = (const float*)d_in[3];

  char* ws = (char*)d_ws;
  int*    gt_idx = (int*)ws;                         // 64*100*4 = 25600 B
  double* acc    = (double*)(ws + 25600);            // 3 doubles
  int*    cnt    = (int*)(ws + 25624);               // 1 int
  double* rowmax = (double*)(ws + 25632);            // 6400 doubles
  double* rowsum = (double*)(ws + 25632 + 51200);    // 6400 doubles

  hipMemsetAsync(ws + 25600, 0, 32, stream);         // zero accumulators
  rowstats_kernel<<<BZ * NQ, 64, 0, stream>>>(lab_preds, rowmax, rowsum);
  match_kernel<<<BZ, 64, 0, stream>>>(labs, lab_preds, bbox, bbox_preds, rowmax, rowsum, gt_idx);
  loss_kernel<<<BZ * NQ, 64, 0, stream>>>(labs, lab_preds, bbox, bbox_preds, gt_idx, acc, cnt);
  finalize_kernel<<<1, 1, 0, stream>>>(acc, cnt, (float*)d_out);
}

// Round 4
// 635.717 us; speedup vs baseline: 3.1317x; 1.1859x over previous
//
#include <hip/hip_runtime.h>
#include <hip/hip_bf16.h>
#include <math.h>
#include <float.h>

#define BZ 64
#define NQ 100
#define NCLS 1203
#define NO_OBJ 1202
constexpr double HUNG_INF = 1e18;
// f64_key(1e18): monotone total-order map of the reference's INF sentinel
#define KINF 0xC3ABC16D674EC800ull

// ---- cross-lane helpers (VALU/scalar, no DS ops) ----
__device__ inline double readlane_f64(double x, int l) {
  int lo = __builtin_amdgcn_readlane(__double2loint(x), l);
  int hi = __builtin_amdgcn_readlane(__double2hiint(x), l);
  return __hiloint2double(hi, lo);
}

template <int CTRL>
__device__ inline unsigned dpp_mov_u32(unsigned x) {
  return (unsigned)__builtin_amdgcn_update_dpp((int)x, (int)x, CTRL, 0xF, 0xF, false);
}
__device__ inline unsigned umin32(unsigned a, unsigned b) { return a < b ? a : b; }

// min over all 64 lanes of a u32, returned wave-uniform (validated DPP recipe)
__device__ inline unsigned wave_min_u32(unsigned x) {
  x = umin32(x, dpp_mov_u32<0xB1>(x));    // quad_perm xor1
  x = umin32(x, dpp_mov_u32<0x4E>(x));    // quad_perm xor2
  x = umin32(x, dpp_mov_u32<0x141>(x));   // row_half_mirror (xor7)
  x = umin32(x, dpp_mov_u32<0x128>(x));   // row_ror:8 -> min over row16
  x = umin32(x, dpp_mov_u32<0x142>(x));   // row_bcast15
  x = umin32(x, dpp_mov_u32<0x143>(x));   // row_bcast31 -> lanes 48-63 global
  return (unsigned)__builtin_amdgcn_readlane((int)x, 63);
}

// monotone bijection f64 <-> u64 (order-preserving for all finite values)
__device__ inline unsigned long long f64_key(double d) {
  unsigned long long b = (unsigned long long)__double_as_longlong(d);
  return (b >> 63) ? ~b : (b | 0x8000000000000000ull);
}
__device__ inline double key_to_f64(unsigned long long k) {
  unsigned long long b = (k >> 63) ? (k & 0x7fffffffffffffffull) : ~k;
  return __longlong_as_double((long long)b);
}

// ---------------- kernel A0: fused per-row stats ----------------
// f64 max & sum(exp) for the matcher; f32 argmax & sum(expf) for the loss.
__global__ __launch_bounds__(64) void rowstats_kernel(
    const float* __restrict__ lab_preds,
    double* __restrict__ rowmax, double* __restrict__ rowsum,
    float* __restrict__ mxf, float* __restrict__ sf, int* __restrict__ amx) {
  const int r = blockIdx.x;
  const int t = threadIdx.x;
  const float* row = lab_preds + (size_t)r * NCLS;
  float fm = -FLT_MAX; int am = NCLS;
  for (int c = t; c < NCLS; c += 64) {
    float vv = row[c];
    if (vv > fm) { fm = vv; am = c; }
  }
#pragma unroll
  for (int off = 32; off; off >>= 1) {
    float ov = __shfl_xor(fm, off); int oi = __shfl_xor(am, off);
    if (ov > fm || (ov == fm && oi < am)) { fm = ov; am = oi; }
  }
  const double mx = (double)fm;   // f64 max of the same floats == f32 max value
  double s = 0.0;
  for (int c = t; c < NCLS; c += 64) s += exp((double)row[c] - mx);
#pragma unroll
  for (int off = 32; off; off >>= 1) s += __shfl_xor(s, off);
  float sfl = 0.0f;
  for (int c = t; c < NCLS; c += 64) sfl += expf(row[c] - fm);
#pragma unroll
  for (int off = 32; off; off >>= 1) sfl += __shfl_xor(sfl, off);
  if (t == 0) {
    rowmax[r] = mx; rowsum[r] = s;
    mxf[r] = fm; sf[r] = sfl; amx[r] = am;
  }
}

// ---------------- kernel A: per-batch cost matrix + Hungarian (JV) ----------------
// Fully register-resident JV: lane l owns columns (l+1), (l+65); per-column
// state (minv, v, way, used, p, u[p]) in registers. Only the cost matrix
// lives in LDS (2 ds_read_b64 per Dijkstra step). Min-reduction runs on a
// monotone u64 key via u32 DPP mins; delta is reconstructed exactly from the
// key (bijective), so all FP values/op-order match the numpy reference
// bit-for-bit, and argmin tie-break is first-min-index via ballot+ffs.
__global__ __launch_bounds__(64) void match_kernel(
    const int* __restrict__ labs, const float* __restrict__ lab_preds,
    const float* __restrict__ bbox, const float* __restrict__ bbox_preds,
    const double* __restrict__ rowmax, const double* __restrict__ rowsum,
    int* __restrict__ gt_idx) {
  __shared__ double Csh[NQ * NQ];   // cost[pred][target], 80 KB
  __shared__ int labs_sh[NQ];
  __shared__ double pxy[NQ][4], txy[NQ][4], pcx[NQ][4], tcx[NQ][4];
  __shared__ double areaP[NQ], areaT[NQ], rmax[NQ], rsum[NQ];

  const int b = blockIdx.x;
  const int lane = threadIdx.x;

  // stage per-batch data into LDS (doubles, mirroring the reference's f64 cast)
  for (int j = lane; j < NQ; j += 64) {
    labs_sh[j] = labs[b * NQ + j];
    const float* tb = bbox + ((size_t)b * NQ + j) * 4;
    double cx = tb[0], cy = tb[1], w = tb[2], h = tb[3];
    tcx[j][0] = cx; tcx[j][1] = cy; tcx[j][2] = w; tcx[j][3] = h;
    double x1 = cx - w * 0.5, y1 = cy - h * 0.5, x2 = cx + w * 0.5, y2 = cy + h * 0.5;
    txy[j][0] = x1; txy[j][1] = y1; txy[j][2] = x2; txy[j][3] = y2;
    areaT[j] = (x2 - x1) * (y2 - y1);
    const float* pb = bbox_preds + ((size_t)b * NQ + j) * 4;
    cx = pb[0]; cy = pb[1]; w = pb[2]; h = pb[3];
    pcx[j][0] = cx; pcx[j][1] = cy; pcx[j][2] = w; pcx[j][3] = h;
    x1 = cx - w * 0.5; y1 = cy - h * 0.5; x2 = cx + w * 0.5; y2 = cy + h * 0.5;
    pxy[j][0] = x1; pxy[j][1] = y1; pxy[j][2] = x2; pxy[j][3] = y2;
    areaP[j] = (x2 - x1) * (y2 - y1);
    rmax[j] = rowmax[b * NQ + j];
    rsum[j] = rowsum[b * NQ + j];
  }
  __syncthreads();

  // fill cost matrix
  for (int idx = lane; idx < NQ * NQ; idx += 64) {
    const int i = idx / NQ, j = idx - i * NQ;
    double pc = exp((double)lab_preds[((size_t)b * NQ + i) * NCLS + labs_sh[j]] - rmax[i]) / rsum[i];
    double cb = fabs(pcx[i][0] - tcx[j][0]) + fabs(pcx[i][1] - tcx[j][1])
              + fabs(pcx[i][2] - tcx[j][2]) + fabs(pcx[i][3] - tcx[j][3]);
    double ltx = fmax(pxy[i][0], txy[j][0]);
    double lty = fmax(pxy[i][1], txy[j][1]);
    double rbx = fmin(pxy[i][2], txy[j][2]);
    double rby = fmin(pxy[i][3], txy[j][3]);
    double inter = fmax(rbx - ltx, 0.0) * fmax(rby - lty, 0.0);
    double uni = areaP[i] + areaT[j] - inter;
    double iou = inter / fmax(uni, 1e-9);
    Csh[idx] = -pc + cb + (1.0 - iou);
  }
  __syncthreads();

  // -------- register-resident Jonker-Volgenant --------
  const bool has1 = (lane + 65 <= NQ);   // lanes 0..35 own a second column
  double v0 = 0.0, v1 = 0.0;
  double u0 = 0.0, u1 = 0.0;             // u[p0c], u[p1c] (valid when p != 0)
  int p0c = 0, p1c = 0;                  // p[] for my columns (0 = unmatched)

  for (int i = 1; i <= NQ; ++i) {
    double minv0 = HUNG_INF, minv1 = HUNG_INF;
    int way0 = 0, way1 = 0;
    bool used0 = false, used1 = false;
    double u_i = 0.0;                    // u[i] for the virgin row (0 at start)
    int j0 = 0, i0 = i;
    double ui0 = 0.0;                    // u[i0]; u[i]==0 first iteration
    while (true) {
      if (j0 == lane + 1) used0 = true;
      if (j0 == lane + 65) used1 = true;

      const double* crow = &Csh[(i0 - 1) * NQ];
      const double c0 = crow[lane];
      const double c1 = has1 ? crow[lane + 64] : 0.0;

      if (!used0) {
        double cur = (c0 - ui0) - v0;
        if (cur < minv0) { minv0 = cur; way0 = j0; }
      }
      if (has1 && !used1) {
        double cur = (c1 - ui0) - v1;
        if (cur < minv1) { minv1 = cur; way1 = j0; }
      }
      const unsigned long long k0 = used0 ? KINF : f64_key(minv0);
      const unsigned long long k1 = has1 ? (used1 ? KINF : f64_key(minv1)) : ~0ull;

      // two-stage u32 min-reduce of the u64 key
      const unsigned h0 = (unsigned)(k0 >> 32), h1 = (unsigned)(k1 >> 32);
      const unsigned KH = wave_min_u32(umin32(h0, h1));
      const unsigned lo0 = (h0 == KH) ? (unsigned)k0 : 0xFFFFFFFFu;
      const unsigned lo1 = (h1 == KH) ? (unsigned)k1 : 0xFFFFFFFFu;
      const unsigned KL = wave_min_u32(umin32(lo0, lo1));
      const unsigned long long KEY = ((unsigned long long)KH << 32) | KL;

      // first-min-index: cols 1..64 (slot0) precede 65..100 (slot1)
      unsigned long long bl0 = __ballot(k0 == KEY);
      int j1, lj;
      if (bl0) { lj = (int)__ffsll(bl0) - 1; j1 = lj + 1; }
      else {
        unsigned long long bl1 = __ballot(k1 == KEY);
        lj = (int)__ffsll(bl1) - 1; j1 = lj + 65;
      }
      const double delta = key_to_f64(KEY);   // exact reference delta

      // potential updates (same per-element op order as reference)
      if (used0)        { v0 -= delta; u0 += delta; }
      else              { minv0 -= delta; }
      if (has1) {
        if (used1)      { v1 -= delta; u1 += delta; }
        else            { minv1 -= delta; }
      }
      u_i += delta;                           // j0=0 is always used

      // advance: i0 = p[j1], ui0 = u[p[j1]] (unchanged this phase: j1 unused)
      int pj1; double uj1;
      if (j1 <= 64) { pj1 = __builtin_amdgcn_readlane(p0c, lj); uj1 = readlane_f64(u0, lj); }
      else          { pj1 = __builtin_amdgcn_readlane(p1c, lj); uj1 = readlane_f64(u1, lj); }
      j0 = j1; i0 = pj1; ui0 = uj1;
      if (pj1 == 0) break;
    }
    // augment along way[] chain; transfer u with p (scalar walk via readlane)
    int jj = j0;
    while (jj != 0) {
      int ljj = (jj <= 64) ? (jj - 1) : (jj - 65);
      int jn = (jj <= 64) ? __builtin_amdgcn_readlane(way0, ljj)
                          : __builtin_amdgcn_readlane(way1, ljj);
      int pn; double un;
      if (jn == 0) { pn = i; un = u_i; }
      else {
        int ln = (jn <= 64) ? (jn - 1) : (jn - 65);
        if (jn <= 64) { pn = __builtin_amdgcn_readlane(p0c, ln); un = readlane_f64(u0, ln); }
        else          { pn = __builtin_amdgcn_readlane(p1c, ln); un = readlane_f64(u1, ln); }
      }
      if (jj == lane + 1)  { p0c = pn; u0 = un; }
      if (jj == lane + 65) { p1c = pn; u1 = un; }
      jj = jn;
    }
  }

  // col_of_row: gt_idx[p[j]-1] = j-1
  gt_idx[b * NQ + p0c - 1] = lane;
  if (has1) gt_idx[b * NQ + p1c - 1] = lane + 64;
}

// ---------------- kernel B: per-row loss from precomputed stats ----------------
__global__ __launch_bounds__(256) void lossfinal_kernel(
    const int* __restrict__ labs, const float* __restrict__ lab_preds,
    const float* __restrict__ bbox, const float* __restrict__ bbox_preds,
    const int* __restrict__ gt_idx,
    const float* __restrict__ mxf, const float* __restrict__ sf,
    const int* __restrict__ amx,
    double* __restrict__ acc, int* __restrict__ cnt_out) {
  const int r = blockIdx.x * 256 + threadIdx.x;
  double lab_t = 0.0, l1_t = 0.0, iou_t = 0.0;
  int c_t = 0;
  if (r < BZ * NQ) {
    const int b = r / NQ;
    const int g = gt_idx[r];
    const int nl = labs[b * NQ + g];
    const float val = lab_preds[(size_t)r * NCLS + nl];
    const float pg = expf(val - mxf[r]) / sf[r];
    lab_t = -(double)pg;
    if (nl != NO_OBJ && nl == amx[r]) {
      c_t = 1;
      const float* pb = bbox_preds + (size_t)r * 4;
      const float* tb = bbox + ((size_t)b * NQ + g) * 4;
      float l1 = fabsf(tb[0] - pb[0]) + fabsf(tb[1] - pb[1])
               + fabsf(tb[2] - pb[2]) + fabsf(tb[3] - pb[3]);
      l1_t = (double)l1;
      float px1 = pb[0] - pb[2] * 0.5f, py1 = pb[1] - pb[3] * 0.5f;
      float px2 = pb[0] + pb[2] * 0.5f, py2 = pb[1] + pb[3] * 0.5f;
      float tx1 = tb[0] - tb[2] * 0.5f, ty1 = tb[1] - tb[3] * 0.5f;
      float tx2 = tb[0] + tb[2] * 0.5f, ty2 = tb[1] + tb[3] * 0.5f;
      float ltx = fmaxf(px1, tx1), lty = fmaxf(py1, ty1);
      float rbx = fminf(px2, tx2), rby = fminf(py2, ty2);
      float inter = fmaxf(rbx - ltx, 0.0f) * fmaxf(rby - lty, 0.0f);
      float uni = (px2 - px1) * (py2 - py1) + (tx2 - tx1) * (ty2 - ty1) - inter;
      float iou = inter / fmaxf(uni, 1e-9f);
      iou_t = (double)(1.0f - iou);
    }
  }
  // wave reduce
#pragma unroll
  for (int off = 32; off; off >>= 1) {
    lab_t += __shfl_xor(lab_t, off);
    l1_t  += __shfl_xor(l1_t, off);
    iou_t += __shfl_xor(iou_t, off);
    c_t   += __shfl_xor(c_t, off);
  }
  __shared__ double s_lab[4], s_l1[4], s_iou[4];
  __shared__ int s_cnt[4];
  const int wave = threadIdx.x >> 6;
  if ((threadIdx.x & 63) == 0) { s_lab[wave] = lab_t; s_l1[wave] = l1_t; s_iou[wave] = iou_t; s_cnt[wave] = c_t; }
  __syncthreads();
  if (threadIdx.x == 0) {
    double a = 0.0, bb = 0.0, c = 0.0; int n = 0;
    for (int w = 0; w < 4; ++w) { a += s_lab[w]; bb += s_l1[w]; c += s_iou[w]; n += s_cnt[w]; }
    atomicAdd(&acc[0], a);
    atomicAdd(&acc[1], bb);
    atomicAdd(&acc[2], c);
    atomicAdd(cnt_out, n);
  }
}

// ---------------- kernel C: combine ----------------
__global__ void finalize_kernel(const double* __restrict__ acc, const int* __restrict__ cnt,
                                float* __restrict__ out) {
  int n = *cnt; if (n < 1) n = 1;
  out[0] = (float)(acc[0] / (double)(BZ * NQ) + acc[1] + acc[2] / (double)n);
}

extern "C" void kernel_launch(void* const* d_in, const int* in_sizes, int n_in,
                              void* d_out, int out_size, void* d_ws, size_t ws_size,
                              hipStream_t stream) {
  const int*   labs       = (const int*)d_in[0];
  const float* lab_preds  = (const float*)d_in[1];
  const float* bbox       = (const float*)d_in[2];
  const float* bbox_preds = (const float*)d_in[3];

  char* ws = (char*)d_ws;
  int*    gt_idx = (int*)ws;                         // 25600 B
  double* acc    = (double*)(ws + 25600);            // 3 doubles
  int*    cnt    = (int*)(ws + 25624);               // 1 int (+4 pad)
  double* rowmax = (double*)(ws + 25632);            // 51200 B
  double* rowsum = (double*)(ws + 76832);            // 51200 B
  float*  mxf    = (float*)(ws + 128032);            // 25600 B
  float*  sfw    = (float*)(ws + 153632);            // 25600 B
  int*    amx    = (int*)(ws + 179232);              // 25600 B

  hipMemsetAsync(ws + 25600, 0, 32, stream);         // zero accumulators
  rowstats_kernel<<<BZ * NQ, 64, 0, stream>>>(lab_preds, rowmax, rowsum, mxf, sfw, amx);
  match_kernel<<<BZ, 64, 0, stream>>>(labs, lab_preds, bbox, bbox_preds, rowmax, rowsum, gt_idx);
  lossfinal_kernel<<<(BZ * NQ + 255) / 256, 256, 0, stream>>>(
      labs, lab_preds, bbox, bbox_preds, gt_idx, mxf, sfw, amx, acc, cnt);
  finalize_kernel<<<1, 1, 0, stream>>>(acc, cnt, (float*)d_out);
}

// Round 5
// 555.548 us; speedup vs baseline: 3.5837x; 1.1443x over previous
//
#include <hip/hip_runtime.h>
#include <hip/hip_bf16.h>
#include <math.h>
#include <float.h>

#define BZ 64
#define NQ 100
#define NCLS 1203
#define NO_OBJ 1202
constexpr double HUNG_INF = 1e18;
// f64_key(1e18): monotone total-order map of the reference's INF sentinel
#define KINF 0xC3ABC16D674EC800ull

// ---- cross-lane helpers (VALU/scalar, no DS ops) ----
__device__ inline double readlane_f64(double x, int l) {
  int lo = __builtin_amdgcn_readlane(__double2loint(x), l);
  int hi = __builtin_amdgcn_readlane(__double2hiint(x), l);
  return __hiloint2double(hi, lo);
}

template <int CTRL>
__device__ inline unsigned dpp_mov_u32(unsigned x) {
  return (unsigned)__builtin_amdgcn_update_dpp((int)x, (int)x, CTRL, 0xF, 0xF, false);
}
__device__ inline unsigned umin32(unsigned a, unsigned b) { return a < b ? a : b; }

// min over all 64 lanes of a u32 -> wave-uniform scalar.
// 4 DPP steps give the full row-16 min in every lane (validated in R3/R4:
// the 6-step variant relied on the same invariant and was bit-exact);
// finish with 4 readlanes + scalar mins.
__device__ inline unsigned wave_min_u32(unsigned x) {
  x = umin32(x, dpp_mov_u32<0xB1>(x));    // quad_perm xor1
  x = umin32(x, dpp_mov_u32<0x4E>(x));    // quad_perm xor2
  x = umin32(x, dpp_mov_u32<0x141>(x));   // row_half_mirror
  x = umin32(x, dpp_mov_u32<0x128>(x));   // row_ror:8 -> row16 min everywhere
  unsigned a = (unsigned)__builtin_amdgcn_readlane((int)x, 0);
  unsigned c = (unsigned)__builtin_amdgcn_readlane((int)x, 16);
  unsigned d = (unsigned)__builtin_amdgcn_readlane((int)x, 32);
  unsigned e = (unsigned)__builtin_amdgcn_readlane((int)x, 48);
  return umin32(umin32(a, c), umin32(d, e));
}

// monotone bijection f64 <-> u64 (order-preserving, branchless)
__device__ inline unsigned long long f64_key(double d) {
  long long b = __double_as_longlong(d);
  long long m = (b >> 63) | (long long)0x8000000000000000ll;
  return (unsigned long long)(b ^ m);
}
__device__ inline double key_to_f64(unsigned long long k) {
  long long kk = (long long)k;
  long long m = ((~kk) >> 63) | (long long)0x8000000000000000ll;
  return __longlong_as_double(kk ^ m);
}

// ---------------- kernel A0: fused per-row stats ----------------
__global__ __launch_bounds__(64) void rowstats_kernel(
    const float* __restrict__ lab_preds,
    double* __restrict__ rowmax, double* __restrict__ rowsum,
    float* __restrict__ mxf, float* __restrict__ sf, int* __restrict__ amx) {
  const int r = blockIdx.x;
  const int t = threadIdx.x;
  const float* row = lab_preds + (size_t)r * NCLS;
  float fm = -FLT_MAX; int am = NCLS;
  for (int c = t; c < NCLS; c += 64) {
    float vv = row[c];
    if (vv > fm) { fm = vv; am = c; }
  }
#pragma unroll
  for (int off = 32; off; off >>= 1) {
    float ov = __shfl_xor(fm, off); int oi = __shfl_xor(am, off);
    if (ov > fm || (ov == fm && oi < am)) { fm = ov; am = oi; }
  }
  const double mx = (double)fm;
  double s = 0.0;
  for (int c = t; c < NCLS; c += 64) s += exp((double)row[c] - mx);
#pragma unroll
  for (int off = 32; off; off >>= 1) s += __shfl_xor(s, off);
  float sfl = 0.0f;
  for (int c = t; c < NCLS; c += 64) sfl += expf(row[c] - fm);
#pragma unroll
  for (int off = 32; off; off >>= 1) sfl += __shfl_xor(sfl, off);
  if (t == 0) {
    rowmax[r] = mx; rowsum[r] = s;
    mxf[r] = fm; sf[r] = sfl; amx[r] = am;
  }
}

// ---------------- kernel A: per-batch cost matrix + Hungarian (JV) ----------------
// Fully register-resident JV. Cost matrix packed as double2 per lane:
// C2[row][lane] = {C[row][lane], C[row][lane+64]} -> one ds_read_b128 per
// Dijkstra step, software-pipelined past the potential updates. Min-reduce
// on hi-32 of a monotone u64 key with exact lo-32 fallback on ties; delta
// reconstructed bijectively -> all FP values/op-order match numpy bit-exact;
// argmin tie-break is first-min-index.
__global__ __launch_bounds__(64) void match_kernel(
    const int* __restrict__ labs, const float* __restrict__ lab_preds,
    const float* __restrict__ bbox, const float* __restrict__ bbox_preds,
    const double* __restrict__ rowmax, const double* __restrict__ rowsum,
    int* __restrict__ gt_idx) {
  __shared__ double2 Csh2[NQ * 64];   // 100 KB, row stride 64 double2 = 1 KB
  __shared__ int labs_sh[NQ];
  __shared__ double pxy[NQ][4], txy[NQ][4], pcx[NQ][4], tcx[NQ][4];
  __shared__ double areaP[NQ], areaT[NQ], rmax[NQ], rsum[NQ];

  const int b = blockIdx.x;
  const int lane = threadIdx.x;

  // stage per-batch data into LDS (doubles, mirroring the reference's f64 cast)
  for (int j = lane; j < NQ; j += 64) {
    labs_sh[j] = labs[b * NQ + j];
    const float* tb = bbox + ((size_t)b * NQ + j) * 4;
    double cx = tb[0], cy = tb[1], w = tb[2], h = tb[3];
    tcx[j][0] = cx; tcx[j][1] = cy; tcx[j][2] = w; tcx[j][3] = h;
    double x1 = cx - w * 0.5, y1 = cy - h * 0.5, x2 = cx + w * 0.5, y2 = cy + h * 0.5;
    txy[j][0] = x1; txy[j][1] = y1; txy[j][2] = x2; txy[j][3] = y2;
    areaT[j] = (x2 - x1) * (y2 - y1);
    const float* pb = bbox_preds + ((size_t)b * NQ + j) * 4;
    cx = pb[0]; cy = pb[1]; w = pb[2]; h = pb[3];
    pcx[j][0] = cx; pcx[j][1] = cy; pcx[j][2] = w; pcx[j][3] = h;
    x1 = cx - w * 0.5; y1 = cy - h * 0.5; x2 = cx + w * 0.5; y2 = cy + h * 0.5;
    pxy[j][0] = x1; pxy[j][1] = y1; pxy[j][2] = x2; pxy[j][3] = y2;
    areaP[j] = (x2 - x1) * (y2 - y1);
    rmax[j] = rowmax[b * NQ + j];
    rsum[j] = rowsum[b * NQ + j];
  }
  __syncthreads();

  // fill cost matrix (packed layout); lane l computes cols l and l+64 of row i
  for (int i = 0; i < NQ; ++i) {
    double cA, cB = 0.0;
    {
      const int j = lane;
      double pc = exp((double)lab_preds[((size_t)b * NQ + i) * NCLS + labs_sh[j]] - rmax[i]) / rsum[i];
      double cb = fabs(pcx[i][0] - tcx[j][0]) + fabs(pcx[i][1] - tcx[j][1])
                + fabs(pcx[i][2] - tcx[j][2]) + fabs(pcx[i][3] - tcx[j][3]);
      double ltx = fmax(pxy[i][0], txy[j][0]);
      double lty = fmax(pxy[i][1], txy[j][1]);
      double rbx = fmin(pxy[i][2], txy[j][2]);
      double rby = fmin(pxy[i][3], txy[j][3]);
      double inter = fmax(rbx - ltx, 0.0) * fmax(rby - lty, 0.0);
      double uni = areaP[i] + areaT[j] - inter;
      double iou = inter / fmax(uni, 1e-9);
      cA = -pc + cb + (1.0 - iou);
    }
    if (lane + 64 < NQ) {
      const int j = lane + 64;
      double pc = exp((double)lab_preds[((size_t)b * NQ + i) * NCLS + labs_sh[j]] - rmax[i]) / rsum[i];
      double cb = fabs(pcx[i][0] - tcx[j][0]) + fabs(pcx[i][1] - tcx[j][1])
                + fabs(pcx[i][2] - tcx[j][2]) + fabs(pcx[i][3] - tcx[j][3]);
      double ltx = fmax(pxy[i][0], txy[j][0]);
      double lty = fmax(pxy[i][1], txy[j][1]);
      double rbx = fmin(pxy[i][2], txy[j][2]);
      double rby = fmin(pxy[i][3], txy[j][3]);
      double inter = fmax(rbx - ltx, 0.0) * fmax(rby - lty, 0.0);
      double uni = areaP[i] + areaT[j] - inter;
      double iou = inter / fmax(uni, 1e-9);
      cB = -pc + cb + (1.0 - iou);
    }
    Csh2[i * 64 + lane] = make_double2(cA, cB);
  }
  __syncthreads();

  // -------- register-resident Jonker-Volgenant --------
  const bool has1 = (lane + 65 <= NQ);   // lanes 0..35 own a second column
  double v0 = 0.0, v1 = 0.0;
  double u0 = 0.0, u1 = 0.0;             // u[p0c], u[p1c] (valid when p != 0)
  int p0c = 0, p1c = 0;                  // p[] for my columns (0 = unmatched)

  for (int i = 1; i <= NQ; ++i) {
    double minv0 = HUNG_INF, minv1 = HUNG_INF;
    int way0 = 0, way1 = 0;
    bool used0 = false, used1 = false;
    double u_i = 0.0;                    // u[i] for the virgin row
    int j0 = 0, i0 = i;
    double ui0 = 0.0;
    double2 cd = Csh2[(i0 - 1) * 64 + lane];   // prologue row fetch
    while (true) {
      if (j0 == lane + 1) used0 = true;
      if (j0 == lane + 65) used1 = true;

      const double c0 = cd.x;
      const double c1 = cd.y;

      if (!used0) {
        double cur = (c0 - ui0) - v0;
        if (cur < minv0) { minv0 = cur; way0 = j0; }
      }
      if (has1 && !used1) {
        double cur = (c1 - ui0) - v1;
        if (cur < minv1) { minv1 = cur; way1 = j0; }
      }
      const unsigned long long k0 = used0 ? KINF : f64_key(minv0);
      const unsigned long long k1 = has1 ? (used1 ? KINF : f64_key(minv1)) : ~0ull;

      // hi-32 reduce; exact lo-32 fallback only on (rare) hi ties
      const unsigned h0 = (unsigned)(k0 >> 32), h1 = (unsigned)(k1 >> 32);
      const unsigned KH = wave_min_u32(umin32(h0, h1));
      unsigned long long blh0 = __ballot(h0 == KH);
      unsigned long long blh1 = __ballot(h1 == KH);
      int j1, lj;
      unsigned long long KEY;
      if (__popcll(blh0) + __popcll(blh1) == 1) {
        if (blh0) {
          lj = (int)__ffsll(blh0) - 1; j1 = lj + 1;
          KEY = ((unsigned long long)KH << 32) |
                (unsigned)__builtin_amdgcn_readlane((int)(unsigned)k0, lj);
        } else {
          lj = (int)__ffsll(blh1) - 1; j1 = lj + 65;
          KEY = ((unsigned long long)KH << 32) |
                (unsigned)__builtin_amdgcn_readlane((int)(unsigned)k1, lj);
        }
      } else {
        const unsigned lo0 = (h0 == KH) ? (unsigned)k0 : 0xFFFFFFFFu;
        const unsigned lo1 = (h1 == KH) ? (unsigned)k1 : 0xFFFFFFFFu;
        const unsigned KL = wave_min_u32(umin32(lo0, lo1));
        KEY = ((unsigned long long)KH << 32) | KL;
        unsigned long long bl0 = __ballot(k0 == KEY);
        if (bl0) { lj = (int)__ffsll(bl0) - 1; j1 = lj + 1; }
        else {
          unsigned long long bl1 = __ballot(k1 == KEY);
          lj = (int)__ffsll(bl1) - 1; j1 = lj + 65;
        }
      }

      // advance pointers first so the next row fetch issues before the updates
      int pj1; double uj1;
      if (j1 <= 64) { pj1 = __builtin_amdgcn_readlane(p0c, lj); uj1 = readlane_f64(u0, lj); }
      else          { pj1 = __builtin_amdgcn_readlane(p1c, lj); uj1 = readlane_f64(u1, lj); }
      const int nrow = (pj1 > 0 ? pj1 : 1) - 1;
      double2 cd_next = Csh2[nrow * 64 + lane];   // ds_read in flight during updates

      const double delta = key_to_f64(KEY);       // exact reference delta
      // potential updates (same per-element op order as reference)
      if (used0)        { v0 -= delta; u0 += delta; }
      else              { minv0 -= delta; }
      if (has1) {
        if (used1)      { v1 -= delta; u1 += delta; }
        else            { minv1 -= delta; }
      }
      u_i += delta;                               // j0=0 is always used

      j0 = j1; i0 = pj1; ui0 = uj1; cd = cd_next;
      if (pj1 == 0) break;
    }
    // augment along way[] chain; transfer u with p (scalar walk via readlane)
    int jj = j0;
    while (jj != 0) {
      int ljj = (jj <= 64) ? (jj - 1) : (jj - 65);
      int jn = (jj <= 64) ? __builtin_amdgcn_readlane(way0, ljj)
                          : __builtin_amdgcn_readlane(way1, ljj);
      int pn; double un;
      if (jn == 0) { pn = i; un = u_i; }
      else {
        int ln = (jn <= 64) ? (jn - 1) : (jn - 65);
        if (jn <= 64) { pn = __builtin_amdgcn_readlane(p0c, ln); un = readlane_f64(u0, ln); }
        else          { pn = __builtin_amdgcn_readlane(p1c, ln); un = readlane_f64(u1, ln); }
      }
      if (jj == lane + 1)  { p0c = pn; u0 = un; }
      if (jj == lane + 65) { p1c = pn; u1 = un; }
      jj = jn;
    }
  }

  // col_of_row: gt_idx[p[j]-1] = j-1
  gt_idx[b * NQ + p0c - 1] = lane;
  if (has1) gt_idx[b * NQ + p1c - 1] = lane + 64;
}

// ---------------- kernel B: per-row loss from precomputed stats ----------------
__global__ __launch_bounds__(256) void lossfinal_kernel(
    const int* __restrict__ labs, const float* __restrict__ lab_preds,
    const float* __restrict__ bbox, const float* __restrict__ bbox_preds,
    const int* __restrict__ gt_idx,
    const float* __restrict__ mxf, const float* __restrict__ sf,
    const int* __restrict__ amx,
    double* __restrict__ acc, int* __restrict__ cnt_out) {
  const int r = blockIdx.x * 256 + threadIdx.x;
  double lab_t = 0.0, l1_t = 0.0, iou_t = 0.0;
  int c_t = 0;
  if (r < BZ * NQ) {
    const int b = r / NQ;
    const int g = gt_idx[r];
    const int nl = labs[b * NQ + g];
    const float val = lab_preds[(size_t)r * NCLS + nl];
    const float pg = expf(val - mxf[r]) / sf[r];
    lab_t = -(double)pg;
    if (nl != NO_OBJ && nl == amx[r]) {
      c_t = 1;
      const float* pb = bbox_preds + (size_t)r * 4;
      const float* tb = bbox + ((size_t)b * NQ + g) * 4;
      float l1 = fabsf(tb[0] - pb[0]) + fabsf(tb[1] - pb[1])
               + fabsf(tb[2] - pb[2]) + fabsf(tb[3] - pb[3]);
      l1_t = (double)l1;
      float px1 = pb[0] - pb[2] * 0.5f, py1 = pb[1] - pb[3] * 0.5f;
      float px2 = pb[0] + pb[2] * 0.5f, py2 = pb[1] + pb[3] * 0.5f;
      float tx1 = tb[0] - tb[2] * 0.5f, ty1 = tb[1] - tb[3] * 0.5f;
      float tx2 = tb[0] + tb[2] * 0.5f, ty2 = tb[1] + tb[3] * 0.5f;
      float ltx = fmaxf(px1, tx1), lty = fmaxf(py1, ty1);
      float rbx = fminf(px2, tx2), rby = fminf(py2, ty2);
      float inter = fmaxf(rbx - ltx, 0.0f) * fmaxf(rby - lty, 0.0f);
      float uni = (px2 - px1) * (py2 - py1) + (tx2 - tx1) * (ty2 - ty1) - inter;
      float iou = inter / fmaxf(uni, 1e-9f);
      iou_t = (double)(1.0f - iou);
    }
  }
#pragma unroll
  for (int off = 32; off; off >>= 1) {
    lab_t += __shfl_xor(lab_t, off);
    l1_t  += __shfl_xor(l1_t, off);
    iou_t += __shfl_xor(iou_t, off);
    c_t   += __shfl_xor(c_t, off);
  }
  __shared__ double s_lab[4], s_l1[4], s_iou[4];
  __shared__ int s_cnt[4];
  const int wave = threadIdx.x >> 6;
  if ((threadIdx.x & 63) == 0) { s_lab[wave] = lab_t; s_l1[wave] = l1_t; s_iou[wave] = iou_t; s_cnt[wave] = c_t; }
  __syncthreads();
  if (threadIdx.x == 0) {
    double a = 0.0, bb = 0.0, c = 0.0; int n = 0;
    for (int w = 0; w < 4; ++w) { a += s_lab[w]; bb += s_l1[w]; c += s_iou[w]; n += s_cnt[w]; }
    atomicAdd(&acc[0], a);
    atomicAdd(&acc[1], bb);
    atomicAdd(&acc[2], c);
    atomicAdd(cnt_out, n);
  }
}

// ---------------- kernel C: combine ----------------
__global__ void finalize_kernel(const double* __restrict__ acc, const int* __restrict__ cnt,
                                float* __restrict__ out) {
  int n = *cnt; if (n < 1) n = 1;
  out[0] = (float)(acc[0] / (double)(BZ * NQ) + acc[1] + acc[2] / (double)n);
}

extern "C" void kernel_launch(void* const* d_in, const int* in_sizes, int n_in,
                              void* d_out, int out_size, void* d_ws, size_t ws_size,
                              hipStream_t stream) {
  const int*   labs       = (const int*)d_in[0];
  const float* lab_preds  = (const float*)d_in[1];
  const float* bbox       = (const float*)d_in[2];
  const float* bbox_preds = (const float*)d_in[3];

  char* ws = (char*)d_ws;
  int*    gt_idx = (int*)ws;                         // 25600 B
  double* acc    = (double*)(ws + 25600);            // 3 doubles
  int*    cnt    = (int*)(ws + 25624);               // 1 int (+4 pad)
  double* rowmax = (double*)(ws + 25632);            // 51200 B
  double* rowsum = (double*)(ws + 76832);            // 51200 B
  float*  mxf    = (float*)(ws + 128032);            // 25600 B
  float*  sfw    = (float*)(ws + 153632);            // 25600 B
  int*    amx    = (int*)(ws + 179232);              // 25600 B

  hipMemsetAsync(ws + 25600, 0, 32, stream);         // zero accumulators
  rowstats_kernel<<<BZ * NQ, 64, 0, stream>>>(lab_preds, rowmax, rowsum, mxf, sfw, amx);
  match_kernel<<<BZ, 64, 0, stream>>>(labs, lab_preds, bbox, bbox_preds, rowmax, rowsum, gt_idx);
  lossfinal_kernel<<<(BZ * NQ + 255) / 256, 256, 0, stream>>>(
      labs, lab_preds, bbox, bbox_preds, gt_idx, mxf, sfw, amx, acc, cnt);
  finalize_kernel<<<1, 1, 0, stream>>>(acc, cnt, (float*)d_out);
}